// Round 14
// baseline (175.556 us; speedup 1.0000x reference)
//
#include <hip/hip_runtime.h>
#include <math.h>

#define BB 2
#define TT 2048
#define DD 1024
#define NH 16
#define NKV 4
#define HD 64
#define EPSF 1.1920929e-07f
// T=2048 > TSL=1024 -> nb = 10000 * 2^(64/62); log2(nb) = log2(1e4) + 64/62
#define LOG2_NB 14.319970444065578
// 0.125 (1/sqrt(64)) * log2(e): folded into q so softmax runs in exp2 domain
#define SCALE_LOG2E 0.18033688011112042f
// fixed softmax max (exp2 units): |q.k| <= 8*8*1.5*0.125*log2e = 17.31 < 17.5
#define FIXMAX 17.5f

typedef __attribute__((ext_vector_type(8))) short bf16x8;
typedef __attribute__((ext_vector_type(4))) float f32x4;

__device__ inline short f2bf(float f) {
    unsigned u = __builtin_bit_cast(unsigned, f);
    unsigned r = (u + 0x7fffu + ((u >> 16) & 1u)) >> 16;
    return (short)r;
}
// packed f32x2 -> bf16x2 (hardware RNE rounding, 1 VALU op)
__device__ inline unsigned cvt_pk_bf16(float a, float b) {
    unsigned r;
    asm("v_cvt_pk_bf16_f32 %0, %1, %2" : "=v"(r) : "v"(a), "v"(b));
    return r;
}

// ---------------- fused fp32 -> bf16 conversion for all 6 tensors + gate-pad zero ----------------
// wb16 layout: rows 0-1023 qw | 1024-1279 kw | 1280-1535 vw | 1536-1551 gw | 1552-1663 zeros
__global__ __launch_bounds__(256) void conv_all(
    const float* __restrict__ x, const float* __restrict__ qw,
    const float* __restrict__ kw, const float* __restrict__ vw,
    const float* __restrict__ ow, const float* __restrict__ gw,
    short* __restrict__ x16, short* __restrict__ wb16, short* __restrict__ ow16)
{
    int i = blockIdx.x * 256 + threadIdx.x;   // float4 index
    if (i >= 1708032) {                        // zero-pad rows 1552-1663 of wb16
        ((short4*)(wb16 + 1552*1024))[i - 1708032] = (short4){0,0,0,0};
        return;
    }
    const float* src; short* dst; int j;
    if (i < 1048576)      { src = x;  dst = x16;            j = i; }
    else if (i < 1310720) { src = qw; dst = wb16;           j = i - 1048576; }
    else if (i < 1376256) { src = kw; dst = wb16 + 1048576; j = i - 1310720; }
    else if (i < 1441792) { src = vw; dst = wb16 + 1310720; j = i - 1376256; }
    else if (i < 1703936) { src = ow; dst = ow16;           j = i - 1441792; }
    else                  { src = gw; dst = wb16 + 1572864; j = i - 1703936; }
    float4 v = ((const float4*)src)[j];
    short4 o;
    o.x = f2bf(v.x); o.y = f2bf(v.y); o.z = f2bf(v.z); o.w = f2bf(v.w);
    ((short4*)dst)[j] = o;
}

// ---------------- staging for 64x128 tiles: A = 1 DMA/wave, B = 2 DMA/wave per K-slice ----------------
#define GSTAGE64(Ab, Bb, k0, Abase, Bbase)                                              \
{                                                                                       \
    {                                                                                   \
        int g = w*64 + lane;                  /* 16B chunk idx, A: 256 chunks */        \
        int row = g >> 2, c = g & 3;                                                    \
        int cg = c ^ (row & 3);               /* XOR swizzle */                         \
        const short* ga = (Abase) + (size_t)(m0 + row)*1024 + (k0) + cg*8;              \
        __builtin_amdgcn_global_load_lds(                                               \
            (const __attribute__((address_space(1))) void*)ga,                          \
            (__attribute__((address_space(3))) void*)((char*)(Ab) + w*1024), 16, 0, 0); \
    }                                                                                   \
    _Pragma("unroll")                                                                   \
    for (int i_ = 0; i_ < 2; i_++) {                                                    \
        int off = w*2048 + i_*1024;                                                     \
        int g = (off >> 4) + lane;            /* B: 512 chunks */                       \
        int row = g >> 2, c = g & 3;                                                    \
        int cg = c ^ (row & 3);                                                         \
        const short* gb = (Bbase) + (size_t)(n0 + row)*1024 + (k0) + cg*8;              \
        __builtin_amdgcn_global_load_lds(                                               \
            (const __attribute__((address_space(1))) void*)gb,                          \
            (__attribute__((address_space(3))) void*)((char*)(Bb) + off), 16, 0, 0);    \
    }                                                                                   \
}

// ring-buffered counted-vmcnt loop (T4): 3 LDS buffers, 2 slices in flight; per step:
// s_waitcnt vmcnt(3) + s_barrier (own slice done, next slice's 3 DMAs stay in flight)
#define GEMM_RING64(KLEN, Abase, Bbase)                                                 \
    GSTAGE64(&As[0][0], &Bs[0][0], 0,  (Abase), (Bbase));                               \
    GSTAGE64(&As[1][0], &Bs[1][0], 32, (Abase), (Bbase));                               \
    {                                                                                   \
        int steps = (KLEN) >> 5;                                                        \
        for (int st = 0; st < steps; st++) {                                            \
            int k0 = st << 5;                                                           \
            int cur = st % 3;                                                           \
            if (st < steps - 1) asm volatile("s_waitcnt vmcnt(3)\n\ts_barrier" ::: "memory"); \
            else                asm volatile("s_waitcnt vmcnt(0)\n\ts_barrier" ::: "memory"); \
            bf16x8 af[2], bfr[4];                                                       \
            _Pragma("unroll")                                                           \
            for (int tm = 0; tm < 2; tm++) {                                            \
                int row = wy*32 + tm*16 + lc;                                           \
                af[tm] = *(const bf16x8*)(&As[cur][0] + row*32 + ((quad*8) ^ ((row&3)*8))); \
            }                                                                           \
            _Pragma("unroll")                                                           \
            for (int tn = 0; tn < 4; tn++) {                                            \
                int row = wx*64 + tn*16 + lc;                                           \
                bfr[tn] = *(const bf16x8*)(&Bs[cur][0] + row*32 + ((quad*8) ^ ((row&3)*8))); \
            }                                                                           \
            if (st + 2 < steps) {                                                       \
                int nxt = (st + 2) % 3;                                                 \
                GSTAGE64(&As[nxt][0], &Bs[nxt][0], k0 + 64, (Abase), (Bbase));          \
            }                                                                           \
            _Pragma("unroll")                                                           \
            for (int tm = 0; tm < 2; tm++)                                              \
                _Pragma("unroll")                                                       \
                for (int tn = 0; tn < 4; tn++)                                          \
                    acc[tm][tn] = __builtin_amdgcn_mfma_f32_16x16x32_bf16(af[tm], bfr[tn], acc[tm][tn], 0, 0, 0); \
        }                                                                               \
    }

// ---------------- QKV+gate GEMM: 64x128 tiles, ring pipeline, fused epilogue ----------------
// Grid dim3(64,13): blockIdx.x = M-panel (bid%8 = panel%8 -> XCD affinity). 832 blocks.
// N-cols: q 0-1023 | k 1024-1279 | v 1280-1535 | gate 1536-1551 | zero-pad.
__global__ __launch_bounds__(256, 4) void gemm_qkv_fused(
    const short* __restrict__ A, const short* __restrict__ Bmat,
    const float* __restrict__ ve, const float* __restrict__ v0,
    const float* __restrict__ q_gain, const float* __restrict__ vr_lambda,
    const float* __restrict__ gb_, float* __restrict__ gate,
    short* __restrict__ qbh, short* __restrict__ kbh, short* __restrict__ vtb,
    float* __restrict__ rawv)
{
    __shared__ short As[3][64*32];
    __shared__ short Bs[3][128*32];
    int tid = threadIdx.x;
    int w = tid >> 6, lane = tid & 63;
    int quad = lane >> 4, lc = lane & 15;
    int wy = w >> 1, wx = w & 1;
    int m0 = blockIdx.x * 64, n0 = blockIdx.y * 128;

    f32x4 acc[2][4];
    #pragma unroll
    for (int i = 0; i < 2; i++)
        #pragma unroll
        for (int j = 0; j < 4; j++) acc[i][j] = (f32x4){0.f,0.f,0.f,0.f};

    GEMM_RING64(1024, A, Bmat);
    __syncthreads();     // LDS reused below; orders epilogue vs. last frag reads

    // ---- fused epilogue ----
    int hc = n0 + wx*64;                 // wave-uniform head column base
    if (hc < 1280) {
        // ---- q or k: RMSNorm over the head + RoPE (partner = tn^2, same lane) ----
        bool isq = (hc < 1024);
        int h = isq ? (hc >> 6) : ((hc - 1024) >> 6);
        float gsc = isq ? (q_gain[h] * SCALE_LOG2E) : 1.0f;
        short* dst = isq ? qbh : kbh;
        int nhh = isq ? 16 : 4;
        float inv0 = (float)exp2((double)lc * (-LOG2_NB / 32.0));
        float inv1 = (float)exp2((double)(lc + 16) * (-LOG2_NB / 32.0));
        #pragma unroll
        for (int tm = 0; tm < 2; tm++) {
            #pragma unroll
            for (int r = 0; r < 4; r++) {
                int m = m0 + wy*32 + tm*16 + quad*4 + r;
                int b = m >> 11, t = m & (TT - 1);
                float a0 = acc[tm][0][r], a1 = acc[tm][1][r];
                float a2 = acc[tm][2][r], a3 = acc[tm][3][r];
                float ss = a0*a0 + a1*a1 + a2*a2 + a3*a3;
                ss += __shfl_xor(ss, 1);
                ss += __shfl_xor(ss, 2);
                ss += __shfl_xor(ss, 4);
                ss += __shfl_xor(ss, 8);     // 16-lane quad holds one row
                float rn = rsqrtf(ss * (1.0f/64.0f) + EPSF);
                a0 *= rn; a1 *= rn; a2 *= rn; a3 *= rn;
                float sn0, cs0, sn1, cs1;
                sincosf((float)t * inv0, &sn0, &cs0);
                sincosf((float)t * inv1, &sn1, &cs1);
                float o0 = a0*cs0 + a2*sn0;      // d in [0,16)
                float o1 = a1*cs1 + a3*sn1;      // d in [16,32)
                float o2 = a2*cs0 - a0*sn0;      // d in [32,48)
                float o3 = a3*cs1 - a1*sn1;      // d in [48,64)
                size_t base = (((size_t)(b*nhh + h))*2048 + t)*64 + lc;
                dst[base +  0] = f2bf(o0 * gsc);
                dst[base + 16] = f2bf(o1 * gsc);
                dst[base + 32] = f2bf(o2 * gsc);
                dst[base + 48] = f2bf(o3 * gsc);
            }
        }
    } else if (hc < 1536) {
        // ---- v: +ve -> rawv ; lambda-mix -> LDS transpose -> vtb [bk][d][t] ----
        int kvh = (hc - 1280) >> 6;
        float l0 = vr_lambda[0], l1 = vr_lambda[1];
        // wave-private 4KB region: w<3 -> As + w*4KB, w==3 -> head of Bs (all dead now)
        short* lbase = (w < 3) ? (short*)((char*)&As[0][0] + w*4096)
                               : (short*)&Bs[0][0];                    // [d][t32]
        #pragma unroll
        for (int tm = 0; tm < 2; tm++) {
            #pragma unroll
            for (int r = 0; r < 4; r++) {
                int m = m0 + wy*32 + tm*16 + quad*4 + r;
                int tl = tm*16 + quad*4 + r;           // t-local (0..31)
                size_t off = (size_t)m*256 + kvh*64 + lc;
                #pragma unroll
                for (int tn = 0; tn < 4; tn++) {
                    int d = tn*16 + lc;
                    float val = acc[tm][tn][r] + ve[off + tn*16];
                    rawv[off + tn*16] = val;
                    // store transposed [d][tl], XOR-swizzled (multiple of 4: keeps pairs)
                    lbase[d*32 + (tl ^ ((d & 7) * 4))] = f2bf(l0 * v0[off + tn*16] + l1 * val);
                }
            }
        }
        // wave-local: no barrier needed (own region, compiler orders LDS w->r)
        int b = m0 >> 11;
        int t0g = (m0 & 2047) + wy*32;
        short* vdst = vtb + (size_t)(b*4 + kvh)*64*2048;
        #pragma unroll
        for (int j = 0; j < 16; j++) {
            int d = quad + j*4;
            int tc = lc*2;
            short2 vv = *(const short2*)&lbase[d*32 + (tc ^ ((d & 7) * 4))];
            *(short2*)&vdst[(size_t)d*2048 + t0g + tc] = vv;
        }
    } else if (hc == 1536) {
        // ---- gate: sigmoid(acc[tm][0] + gb), heads = lc (cols 1536-1551) ----
        #pragma unroll
        for (int tm = 0; tm < 2; tm++)
            #pragma unroll
            for (int r = 0; r < 4; r++) {
                int m = m0 + wy*32 + tm*16 + quad*4 + r;
                float lg = acc[tm][0][r] + gb_[lc];
                gate[(size_t)m*16 + lc] = 1.0f / (1.0f + __expf(-lg));
            }
    }
    // hc == 1600: pad wave, nothing to store
}

// ---------------- out projection GEMM: 64x128 tiles, ring pipeline, XCD affinity ----------------
// grid dim3(64, 8): 512 blocks = 2/CU; bid%8 = M-panel%8
__global__ __launch_bounds__(256, 4) void gemm_mfma(
    const short* __restrict__ A, const short* __restrict__ Bmat,
    float* __restrict__ C, int ldc, int klen)
{
    __shared__ short As[3][64*32];
    __shared__ short Bs[3][128*32];
    int tid = threadIdx.x;
    int w = tid >> 6, lane = tid & 63;
    int quad = lane >> 4, lc = lane & 15;
    int wy = w >> 1, wx = w & 1;
    int m0 = blockIdx.x * 64, n0 = blockIdx.y * 128;

    f32x4 acc[2][4];
    #pragma unroll
    for (int i = 0; i < 2; i++)
        #pragma unroll
        for (int j = 0; j < 4; j++) acc[i][j] = (f32x4){0.f,0.f,0.f,0.f};

    GEMM_RING64(klen, A, Bmat);

    #pragma unroll
    for (int tm = 0; tm < 2; tm++)
        #pragma unroll
        for (int r = 0; r < 4; r++) {
            int m = m0 + wy*32 + tm*16 + quad*4 + r;
            #pragma unroll
            for (int tn = 0; tn < 4; tn++) {
                int n = n0 + wx*64 + tn*16 + lc;
                C[(size_t)m*ldc + n] = acc[tm][tn][r];
            }
        }
}

// ---------------- MFMA flash attention (rounds 0-6 proven form): single Q-tile, 2-buffer,
// ---------------- __syncthreads-drained prefetch, 40KB LDS -> 4 blocks/CU (16 waves/CU TLP) ----------------
__global__ __launch_bounds__(256, 4) void flash_mfma(
    const short* __restrict__ qbh, const short* __restrict__ kbh,
    const short* __restrict__ vtb, const float* __restrict__ gate,
    short* __restrict__ y16)
{
    __shared__ short Ks[2][64*64];
    __shared__ short Vt[2][64*64];
    __shared__ short Ps[4][16*64];   // per wave: row q=lc (16), 64 keys; 8B-chunk XOR swizzle

    int bh = blockIdx.x;             // b*16 + h
    int b = bh >> 4, h = bh & 15, kvh = h >> 2;
    int qt = 31 - blockIdx.y;        // long blocks launch first
    int tid = threadIdx.x;
    int w = tid >> 6, lane = tid & 63;
    int quad = lane >> 4, lc = lane & 15;

    const short* qbase = qbh + (((size_t)bh)*2048 + qt*64 + w*16 + lc)*64;
    bf16x8 qf0 = *(const bf16x8*)(qbase + quad*8);
    bf16x8 qf1 = *(const bf16x8*)(qbase + 32 + quad*8);

    f32x4 o[4];
    #pragma unroll
    for (int i = 0; i < 4; i++) o[i] = (f32x4){0.f,0.f,0.f,0.f};
    f32x4 l4 = (f32x4){0.f,0.f,0.f,0.f};      // l in C-layout via P x ones MFMA
    const bf16x8 ones = {(short)0x3F80,(short)0x3F80,(short)0x3F80,(short)0x3F80,
                         (short)0x3F80,(short)0x3F80,(short)0x3F80,(short)0x3F80};

    const size_t kbase = ((size_t)(b*4 + kvh))*2048*64;   // K [t][d]
    const size_t vbase = ((size_t)(b*4 + kvh))*64*2048;   // V^T [d][t]

    #define STAGE(buf, kt)                                                              \
    {                                                                                   \
        _Pragma("unroll")                                                               \
        for (int i = 0; i < 2; i++) {                                                   \
            int off = w*2048 + i*1024;                                                  \
            int g = (off >> 4) + lane;                                                  \
            int row = g >> 3, c = g & 7;                                                \
            int cg = c ^ (row & 7);                                                     \
            const short* gk = kbh + kbase + (size_t)((kt)*64 + row)*64 + cg*8;          \
            __builtin_amdgcn_global_load_lds(                                           \
                (const __attribute__((address_space(1))) void*)gk,                      \
                (__attribute__((address_space(3))) void*)((char*)Ks[buf] + off), 16, 0, 0); \
            const short* gv = vtb + vbase + (size_t)row*2048 + (kt)*64 + cg*8;          \
            __builtin_amdgcn_global_load_lds(                                           \
                (const __attribute__((address_space(1))) void*)gv,                      \
                (__attribute__((address_space(3))) void*)((char*)Vt[buf] + off), 16, 0, 0); \
        }                                                                               \
    }

    STAGE(0, 0);
    __syncthreads();

    short* ps = Ps[w];

    for (int kt = 0; kt <= qt; kt++) {
        int cur = kt & 1;
        bool diag = (kt == qt);

        // 1. preload ALL K/V fragments for this tile (no LDS reads after DMA issue)
        bf16x8 kf0[4], kf1[4], vf0[4], vf1[4];
        #pragma unroll
        for (int kn = 0; kn < 4; kn++) {
            int row = kn*16 + lc;
            int sw = (row & 7) * 8;
            const short* kr = Ks[cur] + row*64;
            kf0[kn] = *(const bf16x8*)(kr + ((quad*8) ^ sw));
            kf1[kn] = *(const bf16x8*)(kr + ((quad*8 + 32) ^ sw));
            const short* vr = Vt[cur] + row*64;
            vf0[kn] = *(const bf16x8*)(vr + ((quad*8) ^ sw));
            vf1[kn] = *(const bf16x8*)(vr + ((quad*8 + 32) ^ sw));
        }
        // 2. prefetch next K/V tile
        if (kt < qt) STAGE(cur ^ 1, kt + 1);

        // 3. S^T = K Q^T : lane holds cols q=lc, rows key = kn*16 + quad*4 + r
        f32x4 s4[4];
        #pragma unroll
        for (int kn = 0; kn < 4; kn++) {
            f32x4 acc = (f32x4){0.f,0.f,0.f,0.f};
            acc = __builtin_amdgcn_mfma_f32_16x16x32_bf16(kf0[kn], qf0, acc, 0, 0, 0);
            acc = __builtin_amdgcn_mfma_f32_16x16x32_bf16(kf1[kn], qf1, acc, 0, 0, 0);
            s4[kn] = acc;
        }

        // 4. p = exp2(s - FIXMAX) (raw v_exp_f32), causal mask, packed cvt, b64 P store
        #pragma unroll
        for (int kn = 0; kn < 4; kn++) {
            float p0 = __builtin_amdgcn_exp2f(s4[kn][0] - FIXMAX);
            float p1 = __builtin_amdgcn_exp2f(s4[kn][1] - FIXMAX);
            float p2 = __builtin_amdgcn_exp2f(s4[kn][2] - FIXMAX);
            float p3 = __builtin_amdgcn_exp2f(s4[kn][3] - FIXMAX);
            if (diag) {
                int keyb = kn*16 + quad*4, qv = w*16 + lc;
                if (keyb + 0 > qv) p0 = 0.f;
                if (keyb + 1 > qv) p1 = 0.f;
                if (keyb + 2 > qv) p2 = 0.f;
                if (keyb + 3 > qv) p3 = 0.f;
            }
            int c = kn*4 + quad;
            int cs = c ^ ((lc & 7) << 1);
            int2 pk;
            pk.x = (int)cvt_pk_bf16(p0, p1);
            pk.y = (int)cvt_pk_bf16(p2, p3);
            *(int2*)(ps + lc*64 + cs*4) = pk;
        }
        __asm__ volatile("s_waitcnt lgkmcnt(0)" ::: "memory");
        // P A-frags: row q=lc, keys kh*32 + quad*8 + (0..7)
        int u0 = (0*4 + quad) ^ (lc & 7);
        int u1 = (1*4 + quad) ^ (lc & 7);
        bf16x8 pf0 = *(const bf16x8*)(ps + lc*64 + u0*8);
        bf16x8 pf1 = *(const bf16x8*)(ps + lc*64 + u1*8);

        // 5. O += P V ; l4 += P x ones (l lands in C-layout rows quad*4+r)
        #pragma unroll
        for (int dn = 0; dn < 4; dn++) {
            o[dn] = __builtin_amdgcn_mfma_f32_16x16x32_bf16(pf0, vf0[dn], o[dn], 0, 0, 0);
            o[dn] = __builtin_amdgcn_mfma_f32_16x16x32_bf16(pf1, vf1[dn], o[dn], 0, 0, 0);
        }
        l4 = __builtin_amdgcn_mfma_f32_16x16x32_bf16(pf0, ones, l4, 0, 0, 0);
        l4 = __builtin_amdgcn_mfma_f32_16x16x32_bf16(pf1, ones, l4, 0, 0, 0);
        __syncthreads();
    }

    #pragma unroll
    for (int r = 0; r < 4; r++) {
        int row = b*2048 + qt*64 + w*16 + quad*4 + r;
        float g = gate[(size_t)row*16 + h] / l4[r];
        #pragma unroll
        for (int dn = 0; dn < 4; dn++)
            y16[(size_t)row*1024 + h*64 + dn*16 + lc] = f2bf(o[dn][r] * g);
    }
    #undef STAGE
}

extern "C" void kernel_launch(void* const* d_in, const int* in_sizes, int n_in,
                              void* d_out, int out_size, void* d_ws, size_t ws_size,
                              hipStream_t stream) {
    (void)in_sizes; (void)n_in; (void)out_size; (void)ws_size;
    const float* x  = (const float*)d_in[0];
    const float* qw = (const float*)d_in[1];
    const float* kw = (const float*)d_in[2];
    const float* vw = (const float*)d_in[3];
    const float* ow = (const float*)d_in[4];
    const float* ve = (const float*)d_in[5];
    const float* v0 = (const float*)d_in[6];
    const float* qg = (const float*)d_in[7];
    const float* vl = (const float*)d_in[8];
    const float* gw = (const float*)d_in[9];
    const float* gb = (const float*)d_in[10];

    float* out  = (float*)d_out;
    float* rawv = out + (size_t)BB*TT*DD;

    // workspace layout (float units)
    float* p    = (float*)d_ws;
    short* x16  = (short*)p;        p += 2097152;   // 4096*1024 bf16
    short* wb16 = (short*)p;        p += 851968;    // 1664*1024 bf16 (qw|kw|vw|gw|zeros)
    short* ow16 = (short*)p;        p += 524288;    // 1024*1024 bf16
    short* qbh  = (short*)p;        p += 2097152;   // [b*16+h][t][d] bf16
    short* kbh  = (short*)p;        p += 524288;    // [b*4+kvh][t][d] bf16
    short* vtb  = (short*)p;        p += 524288;    // [b*4+kvh][d][t] bf16
    float* gt   = p;                p += 65536;     // 4096*16 f32
    short* y16  = (short*)p;                        // 4096*1024 bf16

    conv_all<<<6784, 256, 0, stream>>>(x, qw, kw, vw, ow, gw, x16, wb16, ow16);
    // QKV+gate projection: 64x128 tiles, 832 blocks (~3.25/CU), ring pipeline
    gemm_qkv_fused<<<dim3(64, 13), 256, 0, stream>>>(x16, wb16, ve, v0, qg, vl,
                                                     gb, gt, qbh, kbh, vtb, rawv);
    // flash (proven form): 1024 single-q-tile blocks, 4 blocks/CU, longest-first
    flash_mfma<<<dim3(32, 32), 256, 0, stream>>>(qbh, kbh, vtb, gt, y16);
    // out projection: 64x128 tiles, 512 blocks (2/CU), ring pipeline
    gemm_mfma<<<dim3(64, 8), 256, 0, stream>>>(y16, ow16, out, 1024, 1024);
}

// Round 15
// 171.422 us; speedup vs baseline: 1.0241x; 1.0241x over previous
//
#include <hip/hip_runtime.h>
#include <math.h>

#define BB 2
#define TT 2048
#define DD 1024
#define NH 16
#define NKV 4
#define HD 64
#define EPSF 1.1920929e-07f
// T=2048 > TSL=1024 -> nb = 10000 * 2^(64/62); log2(nb) = log2(1e4) + 64/62
#define LOG2_NB 14.319970444065578
// 0.125 (1/sqrt(64)) * log2(e): folded into q so softmax runs in exp2 domain
#define SCALE_LOG2E 0.18033688011112042f
// fixed softmax max (exp2 units): |q.k| <= 8*8*1.5*0.125*log2e = 17.31 < 17.5
#define FIXMAX 17.5f

typedef __attribute__((ext_vector_type(8))) short bf16x8;
typedef __attribute__((ext_vector_type(4))) float f32x4;

__device__ inline short f2bf(float f) {
    unsigned u = __builtin_bit_cast(unsigned, f);
    unsigned r = (u + 0x7fffu + ((u >> 16) & 1u)) >> 16;
    return (short)r;
}
// packed f32x2 -> bf16x2 (hardware RNE rounding, 1 VALU op)
__device__ inline unsigned cvt_pk_bf16(float a, float b) {
    unsigned r;
    asm("v_cvt_pk_bf16_f32 %0, %1, %2" : "=v"(r) : "v"(a), "v"(b));
    return r;
}

// ---------------- fused fp32 -> bf16 conversion for all 6 tensors + gate-pad zero ----------------
// wb16 layout: rows 0-1023 qw | 1024-1279 kw | 1280-1535 vw | 1536-1551 gw | 1552-1663 zeros
__global__ __launch_bounds__(256) void conv_all(
    const float* __restrict__ x, const float* __restrict__ qw,
    const float* __restrict__ kw, const float* __restrict__ vw,
    const float* __restrict__ ow, const float* __restrict__ gw,
    short* __restrict__ x16, short* __restrict__ wb16, short* __restrict__ ow16)
{
    int i = blockIdx.x * 256 + threadIdx.x;   // float4 index
    if (i >= 1708032) {                        // zero-pad rows 1552-1663 of wb16
        ((short4*)(wb16 + 1552*1024))[i - 1708032] = (short4){0,0,0,0};
        return;
    }
    const float* src; short* dst; int j;
    if (i < 1048576)      { src = x;  dst = x16;            j = i; }
    else if (i < 1310720) { src = qw; dst = wb16;           j = i - 1048576; }
    else if (i < 1376256) { src = kw; dst = wb16 + 1048576; j = i - 1310720; }
    else if (i < 1441792) { src = vw; dst = wb16 + 1310720; j = i - 1376256; }
    else if (i < 1703936) { src = ow; dst = ow16;           j = i - 1441792; }
    else                  { src = gw; dst = wb16 + 1572864; j = i - 1703936; }
    float4 v = ((const float4*)src)[j];
    short4 o;
    o.x = f2bf(v.x); o.y = f2bf(v.y); o.z = f2bf(v.z); o.w = f2bf(v.w);
    ((short4*)dst)[j] = o;
}

// ---------------- staging for 64x128 tiles: A = 1 DMA/wave, B = 2 DMA/wave per K-slice ----------------
#define GSTAGE64(Ab, Bb, k0, Abase, Bbase)                                              \
{                                                                                       \
    {                                                                                   \
        int g = w*64 + lane;                  /* 16B chunk idx, A: 256 chunks */        \
        int row = g >> 2, c = g & 3;                                                    \
        int cg = c ^ (row & 3);               /* XOR swizzle */                         \
        const short* ga = (Abase) + (size_t)(m0 + row)*1024 + (k0) + cg*8;              \
        __builtin_amdgcn_global_load_lds(                                               \
            (const __attribute__((address_space(1))) void*)ga,                          \
            (__attribute__((address_space(3))) void*)((char*)(Ab) + w*1024), 16, 0, 0); \
    }                                                                                   \
    _Pragma("unroll")                                                                   \
    for (int i_ = 0; i_ < 2; i_++) {                                                    \
        int off = w*2048 + i_*1024;                                                     \
        int g = (off >> 4) + lane;            /* B: 512 chunks */                       \
        int row = g >> 2, c = g & 3;                                                    \
        int cg = c ^ (row & 3);                                                         \
        const short* gb = (Bbase) + (size_t)(n0 + row)*1024 + (k0) + cg*8;              \
        __builtin_amdgcn_global_load_lds(                                               \
            (const __attribute__((address_space(1))) void*)gb,                          \
            (__attribute__((address_space(3))) void*)((char*)(Bb) + off), 16, 0, 0);    \
    }                                                                                   \
}

// ring-buffered counted-vmcnt loop (T4): 3 LDS buffers, 2 slices in flight; per step:
// s_waitcnt vmcnt(3) + s_barrier (own slice done, next slice's 3 DMAs stay in flight)
#define GEMM_RING64(KLEN, Abase, Bbase)                                                 \
    GSTAGE64(&As[0][0], &Bs[0][0], 0,  (Abase), (Bbase));                               \
    GSTAGE64(&As[1][0], &Bs[1][0], 32, (Abase), (Bbase));                               \
    {                                                                                   \
        int steps = (KLEN) >> 5;                                                        \
        for (int st = 0; st < steps; st++) {                                            \
            int k0 = st << 5;                                                           \
            int cur = st % 3;                                                           \
            if (st < steps - 1) asm volatile("s_waitcnt vmcnt(3)\n\ts_barrier" ::: "memory"); \
            else                asm volatile("s_waitcnt vmcnt(0)\n\ts_barrier" ::: "memory"); \
            bf16x8 af[2], bfr[4];                                                       \
            _Pragma("unroll")                                                           \
            for (int tm = 0; tm < 2; tm++) {                                            \
                int row = wy*32 + tm*16 + lc;                                           \
                af[tm] = *(const bf16x8*)(&As[cur][0] + row*32 + ((quad*8) ^ ((row&3)*8))); \
            }                                                                           \
            _Pragma("unroll")                                                           \
            for (int tn = 0; tn < 4; tn++) {                                            \
                int row = wx*64 + tn*16 + lc;                                           \
                bfr[tn] = *(const bf16x8*)(&Bs[cur][0] + row*32 + ((quad*8) ^ ((row&3)*8))); \
            }                                                                           \
            if (st + 2 < steps) {                                                       \
                int nxt = (st + 2) % 3;                                                 \
                GSTAGE64(&As[nxt][0], &Bs[nxt][0], k0 + 64, (Abase), (Bbase));          \
            }                                                                           \
            _Pragma("unroll")                                                           \
            for (int tm = 0; tm < 2; tm++)                                              \
                _Pragma("unroll")                                                       \
                for (int tn = 0; tn < 4; tn++)                                          \
                    acc[tm][tn] = __builtin_amdgcn_mfma_f32_16x16x32_bf16(af[tm], bfr[tn], acc[tm][tn], 0, 0, 0); \
        }                                                                               \
    }

// ---------------- QKV+gate GEMM: 64x128 tiles, ring pipeline, fused epilogue ----------------
// Grid dim3(64,13): blockIdx.x = M-panel (bid%8 = panel%8 -> XCD affinity). 832 blocks.
// N-cols: q 0-1023 | k 1024-1279 | v 1280-1535 | gate 1536-1551 | zero-pad.
__global__ __launch_bounds__(256, 4) void gemm_qkv_fused(
    const short* __restrict__ A, const short* __restrict__ Bmat,
    const float* __restrict__ ve, const float* __restrict__ v0,
    const float* __restrict__ q_gain, const float* __restrict__ vr_lambda,
    const float* __restrict__ gb_, float* __restrict__ gate,
    short* __restrict__ qbh, short* __restrict__ kbh, short* __restrict__ vtb,
    float* __restrict__ rawv)
{
    __shared__ short As[3][64*32];
    __shared__ short Bs[3][128*32];
    int tid = threadIdx.x;
    int w = tid >> 6, lane = tid & 63;
    int quad = lane >> 4, lc = lane & 15;
    int wy = w >> 1, wx = w & 1;
    int m0 = blockIdx.x * 64, n0 = blockIdx.y * 128;

    f32x4 acc[2][4];
    #pragma unroll
    for (int i = 0; i < 2; i++)
        #pragma unroll
        for (int j = 0; j < 4; j++) acc[i][j] = (f32x4){0.f,0.f,0.f,0.f};

    GEMM_RING64(1024, A, Bmat);
    __syncthreads();     // LDS reused below; orders epilogue vs. last frag reads

    // ---- fused epilogue ----
    int hc = n0 + wx*64;                 // wave-uniform head column base
    if (hc < 1280) {
        // ---- q or k: RMSNorm over the head + RoPE (partner = tn^2, same lane) ----
        bool isq = (hc < 1024);
        int h = isq ? (hc >> 6) : ((hc - 1024) >> 6);
        float gsc = isq ? (q_gain[h] * SCALE_LOG2E) : 1.0f;
        short* dst = isq ? qbh : kbh;
        int nhh = isq ? 16 : 4;
        float inv0 = (float)exp2((double)lc * (-LOG2_NB / 32.0));
        float inv1 = (float)exp2((double)(lc + 16) * (-LOG2_NB / 32.0));
        #pragma unroll
        for (int tm = 0; tm < 2; tm++) {
            #pragma unroll
            for (int r = 0; r < 4; r++) {
                int m = m0 + wy*32 + tm*16 + quad*4 + r;
                int b = m >> 11, t = m & (TT - 1);
                float a0 = acc[tm][0][r], a1 = acc[tm][1][r];
                float a2 = acc[tm][2][r], a3 = acc[tm][3][r];
                float ss = a0*a0 + a1*a1 + a2*a2 + a3*a3;
                ss += __shfl_xor(ss, 1);
                ss += __shfl_xor(ss, 2);
                ss += __shfl_xor(ss, 4);
                ss += __shfl_xor(ss, 8);     // 16-lane quad holds one row
                float rn = rsqrtf(ss * (1.0f/64.0f) + EPSF);
                a0 *= rn; a1 *= rn; a2 *= rn; a3 *= rn;
                float sn0, cs0, sn1, cs1;
                sincosf((float)t * inv0, &sn0, &cs0);
                sincosf((float)t * inv1, &sn1, &cs1);
                float o0 = a0*cs0 + a2*sn0;      // d in [0,16)
                float o1 = a1*cs1 + a3*sn1;      // d in [16,32)
                float o2 = a2*cs0 - a0*sn0;      // d in [32,48)
                float o3 = a3*cs1 - a1*sn1;      // d in [48,64)
                size_t base = (((size_t)(b*nhh + h))*2048 + t)*64 + lc;
                dst[base +  0] = f2bf(o0 * gsc);
                dst[base + 16] = f2bf(o1 * gsc);
                dst[base + 32] = f2bf(o2 * gsc);
                dst[base + 48] = f2bf(o3 * gsc);
            }
        }
    } else if (hc < 1536) {
        // ---- v: +ve -> rawv ; lambda-mix -> LDS transpose -> vtb [bk][d][t] ----
        int kvh = (hc - 1280) >> 6;
        float l0 = vr_lambda[0], l1 = vr_lambda[1];
        // wave-private 4KB region: w<3 -> As + w*4KB, w==3 -> head of Bs (all dead now)
        short* lbase = (w < 3) ? (short*)((char*)&As[0][0] + w*4096)
                               : (short*)&Bs[0][0];                    // [d][t32]
        #pragma unroll
        for (int tm = 0; tm < 2; tm++) {
            #pragma unroll
            for (int r = 0; r < 4; r++) {
                int m = m0 + wy*32 + tm*16 + quad*4 + r;
                int tl = tm*16 + quad*4 + r;           // t-local (0..31)
                size_t off = (size_t)m*256 + kvh*64 + lc;
                #pragma unroll
                for (int tn = 0; tn < 4; tn++) {
                    int d = tn*16 + lc;
                    float val = acc[tm][tn][r] + ve[off + tn*16];
                    rawv[off + tn*16] = val;
                    // store transposed [d][tl], XOR-swizzled (multiple of 4: keeps pairs)
                    lbase[d*32 + (tl ^ ((d & 7) * 4))] = f2bf(l0 * v0[off + tn*16] + l1 * val);
                }
            }
        }
        // wave-local: no barrier needed (own region, compiler orders LDS w->r)
        int b = m0 >> 11;
        int t0g = (m0 & 2047) + wy*32;
        short* vdst = vtb + (size_t)(b*4 + kvh)*64*2048;
        #pragma unroll
        for (int j = 0; j < 16; j++) {
            int d = quad + j*4;
            int tc = lc*2;
            short2 vv = *(const short2*)&lbase[d*32 + (tc ^ ((d & 7) * 4))];
            *(short2*)&vdst[(size_t)d*2048 + t0g + tc] = vv;
        }
    } else if (hc == 1536) {
        // ---- gate: sigmoid(acc[tm][0] + gb), heads = lc (cols 1536-1551) ----
        #pragma unroll
        for (int tm = 0; tm < 2; tm++)
            #pragma unroll
            for (int r = 0; r < 4; r++) {
                int m = m0 + wy*32 + tm*16 + quad*4 + r;
                float lg = acc[tm][0][r] + gb_[lc];
                gate[(size_t)m*16 + lc] = 1.0f / (1.0f + __expf(-lg));
            }
    }
    // hc == 1600: pad wave, nothing to store
}

// ---------------- out projection GEMM: 64x128 tiles, ring pipeline, XCD affinity ----------------
// grid dim3(64, 8): 512 blocks = 2/CU; bid%8 = M-panel%8
__global__ __launch_bounds__(256, 4) void gemm_mfma(
    const short* __restrict__ A, const short* __restrict__ Bmat,
    float* __restrict__ C, int ldc, int klen)
{
    __shared__ short As[3][64*32];
    __shared__ short Bs[3][128*32];
    int tid = threadIdx.x;
    int w = tid >> 6, lane = tid & 63;
    int quad = lane >> 4, lc = lane & 15;
    int wy = w >> 1, wx = w & 1;
    int m0 = blockIdx.x * 64, n0 = blockIdx.y * 128;

    f32x4 acc[2][4];
    #pragma unroll
    for (int i = 0; i < 2; i++)
        #pragma unroll
        for (int j = 0; j < 4; j++) acc[i][j] = (f32x4){0.f,0.f,0.f,0.f};

    GEMM_RING64(klen, A, Bmat);

    #pragma unroll
    for (int tm = 0; tm < 2; tm++)
        #pragma unroll
        for (int r = 0; r < 4; r++) {
            int m = m0 + wy*32 + tm*16 + quad*4 + r;
            #pragma unroll
            for (int tn = 0; tn < 4; tn++) {
                int n = n0 + wx*64 + tn*16 + lc;
                C[(size_t)m*ldc + n] = acc[tm][tn][r];
            }
        }
}

// ---------------- MFMA flash attention v5: paired Q-tiles (j, 31-j), ring K/V staging ----------------
// Each block handles Q-tiles qlo=j and qhi=31-j of one (b,h): combined compute = 33
// tile-steps for every block (perfect balance), K/V staged ONCE for both. 3-buffer ring
// with counted vmcnt (T4). Grid dim3(32 bh, 16 j), 2 blocks/CU.
__global__ __launch_bounds__(256, 2) void flash_mfma(
    const short* __restrict__ qbh, const short* __restrict__ kbh,
    const short* __restrict__ vtb, const float* __restrict__ gate,
    short* __restrict__ y16)
{
    __shared__ short Ks[3][64*64];
    __shared__ short Vt[3][64*64];
    __shared__ short Ps[8][16*64];   // [0..3]=hi per wave, [4..7]=lo per wave

    int bh = blockIdx.x;             // b*16 + h
    int b = bh >> 4, h = bh & 15, kvh = h >> 2;
    int j = blockIdx.y;              // 0..15
    int qlo = j, qhi = 31 - j;
    int tid = threadIdx.x;
    int w = tid >> 6, lane = tid & 63;
    int quad = lane >> 4, lc = lane & 15;

    const short* qbaseL = qbh + (((size_t)bh)*2048 + qlo*64 + w*16 + lc)*64;
    bf16x8 qfL0 = *(const bf16x8*)(qbaseL + quad*8);
    bf16x8 qfL1 = *(const bf16x8*)(qbaseL + 32 + quad*8);
    const short* qbaseH = qbh + (((size_t)bh)*2048 + qhi*64 + w*16 + lc)*64;
    bf16x8 qfH0 = *(const bf16x8*)(qbaseH + quad*8);
    bf16x8 qfH1 = *(const bf16x8*)(qbaseH + 32 + quad*8);

    f32x4 oL[4], oH[4];
    #pragma unroll
    for (int i = 0; i < 4; i++) { oL[i] = (f32x4){0.f,0.f,0.f,0.f}; oH[i] = (f32x4){0.f,0.f,0.f,0.f}; }
    f32x4 lL = (f32x4){0.f,0.f,0.f,0.f};
    f32x4 lH = (f32x4){0.f,0.f,0.f,0.f};
    const bf16x8 ones = {(short)0x3F80,(short)0x3F80,(short)0x3F80,(short)0x3F80,
                         (short)0x3F80,(short)0x3F80,(short)0x3F80,(short)0x3F80};

    const size_t kbase = ((size_t)(b*4 + kvh))*2048*64;   // K [t][d]
    const size_t vbase = ((size_t)(b*4 + kvh))*64*2048;   // V^T [d][t]

    #define STAGE(buf, kt)                                                              \
    {                                                                                   \
        _Pragma("unroll")                                                               \
        for (int i = 0; i < 2; i++) {                                                   \
            int off = w*2048 + i*1024;                                                  \
            int g = (off >> 4) + lane;                                                  \
            int row = g >> 3, c = g & 7;                                                \
            int cg = c ^ (row & 7);                                                     \
            const short* gk = kbh + kbase + (size_t)((kt)*64 + row)*64 + cg*8;          \
            __builtin_amdgcn_global_load_lds(                                           \
                (const __attribute__((address_space(1))) void*)gk,                      \
                (__attribute__((address_space(3))) void*)((char*)Ks[buf] + off), 16, 0, 0); \
            const short* gv = vtb + vbase + (size_t)row*2048 + (kt)*64 + cg*8;          \
            __builtin_amdgcn_global_load_lds(                                           \
                (const __attribute__((address_space(1))) void*)gv,                      \
                (__attribute__((address_space(3))) void*)((char*)Vt[buf] + off), 16, 0, 0); \
        }                                                                               \
    }

    // one QK^T + softmax + PV step against the current K/V frags
    #define ATT_TILE(qf0_, qf1_, oacc, lacc, ps_, qtv)                                  \
    {                                                                                   \
        f32x4 s4[4];                                                                    \
        _Pragma("unroll")                                                               \
        for (int kn = 0; kn < 4; kn++) {                                                \
            f32x4 a_ = (f32x4){0.f,0.f,0.f,0.f};                                        \
            a_ = __builtin_amdgcn_mfma_f32_16x16x32_bf16(kf0[kn], qf0_, a_, 0, 0, 0);   \
            a_ = __builtin_amdgcn_mfma_f32_16x16x32_bf16(kf1[kn], qf1_, a_, 0, 0, 0);   \
            s4[kn] = a_;                                                                \
        }                                                                               \
        bool diag = (kt == (qtv));                                                      \
        _Pragma("unroll")                                                               \
        for (int kn = 0; kn < 4; kn++) {                                                \
            float p0 = __builtin_amdgcn_exp2f(s4[kn][0] - FIXMAX);                      \
            float p1 = __builtin_amdgcn_exp2f(s4[kn][1] - FIXMAX);                      \
            float p2 = __builtin_amdgcn_exp2f(s4[kn][2] - FIXMAX);                      \
            float p3 = __builtin_amdgcn_exp2f(s4[kn][3] - FIXMAX);                      \
            if (diag) {                                                                 \
                int keyb = kn*16 + quad*4, qv = w*16 + lc;                              \
                if (keyb + 0 > qv) p0 = 0.f;                                            \
                if (keyb + 1 > qv) p1 = 0.f;                                            \
                if (keyb + 2 > qv) p2 = 0.f;                                            \
                if (keyb + 3 > qv) p3 = 0.f;                                            \
            }                                                                           \
            int c = kn*4 + quad;                                                        \
            int cs = c ^ ((lc & 7) << 1);                                               \
            int2 pk;                                                                    \
            pk.x = (int)cvt_pk_bf16(p0, p1);                                            \
            pk.y = (int)cvt_pk_bf16(p2, p3);                                            \
            *(int2*)((ps_) + lc*64 + cs*4) = pk;                                        \
        }                                                                               \
        __asm__ volatile("s_waitcnt lgkmcnt(0)" ::: "memory");                          \
        int u0 = (0*4 + quad) ^ (lc & 7);                                               \
        int u1 = (1*4 + quad) ^ (lc & 7);                                               \
        bf16x8 pf0 = *(const bf16x8*)((ps_) + lc*64 + u0*8);                            \
        bf16x8 pf1 = *(const bf16x8*)((ps_) + lc*64 + u1*8);                            \
        _Pragma("unroll")                                                               \
        for (int dn = 0; dn < 4; dn++) {                                                \
            oacc[dn] = __builtin_amdgcn_mfma_f32_16x16x32_bf16(pf0, vf0[dn], oacc[dn], 0, 0, 0); \
            oacc[dn] = __builtin_amdgcn_mfma_f32_16x16x32_bf16(pf1, vf1[dn], oacc[dn], 0, 0, 0); \
        }                                                                               \
        lacc = __builtin_amdgcn_mfma_f32_16x16x32_bf16(pf0, ones, lacc, 0, 0, 0);       \
        lacc = __builtin_amdgcn_mfma_f32_16x16x32_bf16(pf1, ones, lacc, 0, 0, 0);       \
    }

    // ring prologue: two K/V tiles in flight (qhi >= 16, so tiles 0,1 always exist)
    STAGE(0, 0);
    STAGE(1, 1);

    short* psH = Ps[w];
    short* psL = Ps[4 + w];

    for (int kt = 0; kt <= qhi; kt++) {
        int cur = kt % 3;
        // wait own tile (next tile's 4 DMAs stay in flight), then barrier
        if (kt < qhi) asm volatile("s_waitcnt vmcnt(4)\n\ts_barrier" ::: "memory");
        else          asm volatile("s_waitcnt vmcnt(0)\n\ts_barrier" ::: "memory");

        // preload ALL K/V fragments for this tile
        bf16x8 kf0[4], kf1[4], vf0[4], vf1[4];
        #pragma unroll
        for (int kn = 0; kn < 4; kn++) {
            int row = kn*16 + lc;
            int sw = (row & 7) * 8;
            const short* kr = Ks[cur] + row*64;
            kf0[kn] = *(const bf16x8*)(kr + ((quad*8) ^ sw));
            kf1[kn] = *(const bf16x8*)(kr + ((quad*8 + 32) ^ sw));
            const short* vr = Vt[cur] + row*64;
            vf0[kn] = *(const bf16x8*)(vr + ((quad*8) ^ sw));
            vf1[kn] = *(const bf16x8*)(vr + ((quad*8 + 32) ^ sw));
        }
        // prefetch tile kt+2 into buffer (kt+2)%3 (last read at iteration kt-1, pre-barrier)
        if (kt + 2 <= qhi) STAGE((kt + 2) % 3, kt + 2);

        // hi Q-tile: always active
        ATT_TILE(qfH0, qfH1, oH, lH, psH, qhi);
        // lo Q-tile: active while kt <= qlo (wave-uniform branch)
        if (kt <= qlo) ATT_TILE(qfL0, qfL1, oL, lL, psL, qlo);
    }

    #pragma unroll
    for (int r = 0; r < 4; r++) {
        int rowH = b*2048 + qhi*64 + w*16 + quad*4 + r;
        float gH = gate[(size_t)rowH*16 + h] / lH[r];
        int rowL = b*2048 + qlo*64 + w*16 + quad*4 + r;
        float gL = gate[(size_t)rowL*16 + h] / lL[r];
        #pragma unroll
        for (int dn = 0; dn < 4; dn++) {
            y16[(size_t)rowH*1024 + h*64 + dn*16 + lc] = f2bf(oH[dn][r] * gH);
            y16[(size_t)rowL*1024 + h*64 + dn*16 + lc] = f2bf(oL[dn][r] * gL);
        }
    }
    #undef STAGE
    #undef ATT_TILE
}

extern "C" void kernel_launch(void* const* d_in, const int* in_sizes, int n_in,
                              void* d_out, int out_size, void* d_ws, size_t ws_size,
                              hipStream_t stream) {
    (void)in_sizes; (void)n_in; (void)out_size; (void)ws_size;
    const float* x  = (const float*)d_in[0];
    const float* qw = (const float*)d_in[1];
    const float* kw = (const float*)d_in[2];
    const float* vw = (const float*)d_in[3];
    const float* ow = (const float*)d_in[4];
    const float* ve = (const float*)d_in[5];
    const float* v0 = (const float*)d_in[6];
    const float* qg = (const float*)d_in[7];
    const float* vl = (const float*)d_in[8];
    const float* gw = (const float*)d_in[9];
    const float* gb = (const float*)d_in[10];

    float* out  = (float*)d_out;
    float* rawv = out + (size_t)BB*TT*DD;

    // workspace layout (float units)
    float* p    = (float*)d_ws;
    short* x16  = (short*)p;        p += 2097152;   // 4096*1024 bf16
    short* wb16 = (short*)p;        p += 851968;    // 1664*1024 bf16 (qw|kw|vw|gw|zeros)
    short* ow16 = (short*)p;        p += 524288;    // 1024*1024 bf16
    short* qbh  = (short*)p;        p += 2097152;   // [b*16+h][t][d] bf16
    short* kbh  = (short*)p;        p += 524288;    // [b*4+kvh][t][d] bf16
    short* vtb  = (short*)p;        p += 524288;    // [b*4+kvh][d][t] bf16
    float* gt   = p;                p += 65536;     // 4096*16 f32
    short* y16  = (short*)p;                        // 4096*1024 bf16

    conv_all<<<6784, 256, 0, stream>>>(x, qw, kw, vw, ow, gw, x16, wb16, ow16);
    // QKV+gate projection: 64x128 tiles, 832 blocks (~3.25/CU), ring pipeline
    gemm_qkv_fused<<<dim3(64, 13), 256, 0, stream>>>(x16, wb16, ve, v0, qg, vl,
                                                     gb, gt, qbh, kbh, vtb, rawv);
    // flash: paired Q-tiles (j, 31-j), 512 balanced blocks
    flash_mfma<<<dim3(32, 16), 256, 0, stream>>>(qbh, kbh, vtb, gt, y16);
    // out projection: 64x128 tiles, 512 blocks (2/CU), ring pipeline
    gemm_mfma<<<dim3(64, 8), 256, 0, stream>>>(y16, ow16, out, 1024, 1024);
}